// Round 10
// baseline (158.964 us; speedup 1.0000x reference)
//
#include <hip/hip_runtime.h>
#include <hip/hip_bf16.h>
#include <math.h>

#define Nn 4096
#define Hdim 256
#define Edim 128
#define Cdim 32
#define Vdim 64
#define Kdim 20
#define G4H 1024
#define OUTS 513

#define NB 8
#define LMAXL 160
#define MAXG (NB * LMAXL)   // 1280 lstm slots (32-row tiles)
#define MAXT2 192           // loss slots
#define GRID (MAXG + MAXT2)
#define DYN_LDS 73728       // 2x(32K W + 4K X)

typedef short bf16x8 __attribute__((ext_vector_type(8)));
typedef float f32x4 __attribute__((ext_vector_type(4)));

__device__ __forceinline__ float sigmoidf_(float x) { return 1.0f / (1.0f + expf(-x)); }

__device__ __forceinline__ bf16x8 cvt8(float4 f0, float4 f1) {
    bf16x8 r;
    __hip_bfloat16 h;
    h = __float2bfloat16(f0.x); r[0] = *(short*)&h;
    h = __float2bfloat16(f0.y); r[1] = *(short*)&h;
    h = __float2bfloat16(f0.z); r[2] = *(short*)&h;
    h = __float2bfloat16(f0.w); r[3] = *(short*)&h;
    h = __float2bfloat16(f1.x); r[4] = *(short*)&h;
    h = __float2bfloat16(f1.y); r[5] = *(short*)&h;
    h = __float2bfloat16(f1.z); r[6] = *(short*)&h;
    h = __float2bfloat16(f1.w); r[7] = *(short*)&h;
    return r;
}

__device__ __forceinline__ void gl_lds16(const float* g, void* l) {
    __builtin_amdgcn_global_load_lds((const __attribute__((address_space(1))) void*)g,
                                     (__attribute__((address_space(3))) void*)l, 16, 0, 0);
}

__device__ __forceinline__ int swz(int r) { return ((r & 3) << 1) | ((r >> 2) & 1); }

// raw barrier + fine-grained vmcnt (AITER-style pipeline primitives)
#define RBAR()   asm volatile("s_barrier" ::: "memory")
#define WAITV9() asm volatile("s_waitcnt vmcnt(9)" ::: "memory")
#define WAITV0() asm volatile("s_waitcnt vmcnt(0)" ::: "memory")

// ================= single fused kernel =================
__global__ __launch_bounds__(256) void k_all(
    const float* __restrict__ vec, const float* __restrict__ inp,
    const float* __restrict__ h_prev, const float* __restrict__ c_prev,
    const float* __restrict__ Wlin, const float* __restrict__ blin,
    const float* __restrict__ Wec, const float* __restrict__ bec,
    const float* __restrict__ Wrel, const float* __restrict__ brel,
    const float* __restrict__ W_ih, const float* __restrict__ b_ih,
    const float* __restrict__ W_hh, const float* __restrict__ b_hh,
    const int* __restrict__ category, const int* __restrict__ cell_id,
    const int* __restrict__ true_idx, const int* __restrict__ ec_idx, const int* __restrict__ rel_idx,
    float* __restrict__ out)
{
    extern __shared__ __align__(16) char smem[];
    int* cntR = (int*)smem;                 // setup scratch (consumed into regs before staging)
    int* cntF = (int*)(smem + 8192);
    int* wsum = (int*)(smem + 8320);
    int* rows_tmp = (int*)(smem + 8448);

    int t = threadIdx.x;
    int w = t >> 6, l = t & 63;
    int l15 = l & 15, quad = l >> 4;
    int lrow8 = l >> 3, lslot = l & 7;
    bool is_lstm = blockIdx.x < MAXG;
    const int* key = is_lstm ? cell_id : category;
    int nbins = is_lstm ? Kdim : Cdim;

    // ---- histogram (x16 replicated) ----
    for (int i = t; i < nbins * 16; i += 256) cntR[i] = 0;
    __syncthreads();
    int4 kv0 = ((const int4*)key)[t * 4 + 0];
    int4 kv1 = ((const int4*)key)[t * 4 + 1];
    int4 kv2 = ((const int4*)key)[t * 4 + 2];
    int4 kv3 = ((const int4*)key)[t * 4 + 3];
    int ks[16] = { kv0.x, kv0.y, kv0.z, kv0.w, kv1.x, kv1.y, kv1.z, kv1.w,
                   kv2.x, kv2.y, kv2.z, kv2.w, kv3.x, kv3.y, kv3.z, kv3.w };
    int rep = t & 15;
    #pragma unroll
    for (int j = 0; j < 16; j++) atomicAdd(&cntR[ks[j] * 16 + rep], 1);
    __syncthreads();
    if (t < nbins) {
        int s2 = 0;
        #pragma unroll
        for (int r2 = 0; r2 < 16; r2++) s2 += cntR[t * 16 + r2];
        cntF[t] = s2;
    }
    __syncthreads();

    // ---- direct slot decode ----
    int myk, s_idx, hb0 = 0, rcount, wlen;
    if (is_lstm) {
        int b = blockIdx.x & 7, pos = blockIdx.x >> 3;
        int u = -1, sf = 0, acc = 0;
        for (int uu = b; uu < Kdim * 4; uu += NB) {
            int n = (cntF[uu >> 2] + 31) >> 5;
            if (u < 0 && pos < acc + n) { u = uu; sf = pos - acc; }
            acc += n;
        }
        if (u < 0) return;
        myk = u >> 2; hb0 = (u & 3) * 64; s_idx = sf;
        wlen = 32;
        rcount = min(32, cntF[myk] - s_idx * 32);
    } else {
        int slot = blockIdx.x - MAXG;
        int u = -1, sf = 0, acc = 0;
        for (int m = 0; m < Cdim; m++) {
            int n = (cntF[m] + 31) >> 5;
            if (u < 0 && slot < acc + n) { u = m; sf = slot - acc; }
            acc += n;
        }
        if (u < 0) return;
        myk = u; s_idx = sf;
        wlen = 32;
        rcount = min(32, cntF[myk] - s_idx * 32);
    }

    // ---- rank-select via wave shfl scan ----
    {
        int local = 0;
        #pragma unroll
        for (int j = 0; j < 16; j++) local += (ks[j] == myk) ? 1 : 0;
        int v = local;
        #pragma unroll
        for (int off = 1; off < 64; off <<= 1) {
            int n = __shfl_up(v, off);
            if (l >= off) v += n;
        }
        if (l == 63) wsum[w] = v;
        __syncthreads();
        int wbase = 0;
        #pragma unroll
        for (int ww = 0; ww < 4; ww++) wbase += (ww < w) ? wsum[ww] : 0;
        int rank = wbase + v - local;
        int w0 = s_idx * wlen;
        #pragma unroll
        for (int j = 0; j < 16; j++) {
            if (ks[j] == myk) {
                int rr = rank - w0;
                if (rr >= 0 && rr < wlen) rows_tmp[rr] = t * 16 + j;
                rank++;
            }
        }
        __syncthreads();
        if (t < wlen && t >= rcount) rows_tmp[t] = rows_tmp[0];
        __syncthreads();
    }
    int reg_row = rows_tmp[l & 31];   // consumed into registers; scratch LDS free now
    int swz_l = swz(l15);
    int p0 = (quad * 2) ^ swz_l;

    if (is_lstm) {
        // ============ LSTM: 32 rows x (64h x 4 gates), K=384, double-buffered DMA pipeline ============
        const float* Wih_k = W_ih + (size_t)myk * G4H * Edim;
        const float* Whh_k = W_hh + (size_t)myk * G4H * Hdim;

        int xr = w * 8 + lrow8;
        int xrow = __shfl(reg_row, xr);
        int xg = lslot ^ swz(xr);

        f32x4 acc[2][4];
        #pragma unroll
        for (int m = 0; m < 2; m++)
            #pragma unroll
            for (int g = 0; g < 4; g++)
                acc[m][g] = (f32x4){0.f, 0.f, 0.f, 0.f};

        // stage step st into buffer sel: 9 DMA instrs per wave (8 W + 1 X)
        auto stage = [&](int st, int sel) {
            int k0 = st * 32;
            const float* Wsrc; int stride, ko;
            if (k0 < Edim) { Wsrc = Wih_k; stride = Edim; ko = k0; }
            else           { Wsrc = Whh_k; stride = Hdim; ko = k0 - Edim; }
            char* wb = smem + sel * 32768;
            char* xb = smem + 65536 + sel * 4096;
            #pragma unroll
            for (int j = 0; j < 8; j++) {
                int r = w * 64 + j * 8 + lrow8;
                int g = lslot ^ swz(r);
                int gate = r >> 6, hl = r & 63;
                gl_lds16(Wsrc + (size_t)(gate * Hdim + hb0 + hl) * stride + ko + g * 4,
                         wb + (w * 64 + j * 8) * 128);
            }
            const float* xs = (k0 < Edim) ? inp + (size_t)xrow * Edim + ko
                                          : h_prev + (size_t)xrow * Hdim + ko;
            gl_lds16(xs + xg * 4, xb + (w * 8) * 128);
        };

        // rank-select barrier above guarantees scratch reads done before buf0 staging
        stage(0, 0);
        for (int st = 0; st < 12; st++) {
            int sel = st & 1;
            if (st < 11) { stage(st + 1, sel ^ 1); WAITV9(); }
            else         { WAITV0(); }
            RBAR();   // buf[sel] fully landed for ALL waves
            {
                float* Wbuf = (float*)(smem + sel * 32768);
                float* Xbuf = (float*)(smem + 65536 + sel * 4096);
                bf16x8 af[2], bfr[4];
                #pragma unroll
                for (int m = 0; m < 2; m++) {
                    int row = m * 16 + l15;
                    float4 lo = *(float4*)(Xbuf + row * 32 + p0 * 4);
                    float4 hi = *(float4*)(Xbuf + row * 32 + (p0 ^ 1) * 4);
                    af[m] = cvt8(lo, hi);
                }
                #pragma unroll
                for (int g = 0; g < 4; g++) {
                    int row = g * 64 + w * 16 + l15;
                    float4 lo = *(float4*)(Wbuf + row * 32 + p0 * 4);
                    float4 hi = *(float4*)(Wbuf + row * 32 + (p0 ^ 1) * 4);
                    bfr[g] = cvt8(lo, hi);
                }
                #pragma unroll
                for (int m = 0; m < 2; m++)
                    #pragma unroll
                    for (int g = 0; g < 4; g++)
                        acc[m][g] = __builtin_amdgcn_mfma_f32_16x16x32_bf16(af[m], bfr[g], acc[m][g], 0, 0, 0);
            }
            RBAR();   // all waves done reading buf[sel] before it is re-staged next iter
        }

        int h = hb0 + w * 16 + l15;
        float bs[4];
        #pragma unroll
        for (int g = 0; g < 4; g++)
            bs[g] = b_ih[(size_t)myk * G4H + g * Hdim + h] + b_hh[(size_t)myk * G4H + g * Hdim + h];

        #pragma unroll
        for (int m = 0; m < 2; m++) {
            #pragma unroll
            for (int reg = 0; reg < 4; reg++) {
                int r = m * 16 + quad * 4 + reg;
                int row = __shfl(reg_row, r);
                if (r < rcount) {
                    float iv = acc[m][0][reg] + bs[0];
                    float fv = acc[m][1][reg] + bs[1];
                    float gv = acc[m][2][reg] + bs[2];
                    float ov = acc[m][3][reg] + bs[3];
                    float cp = c_prev[(size_t)row * Hdim + h];
                    float cn = sigmoidf_(fv) * cp + sigmoidf_(iv) * tanhf(gv);
                    float hn = sigmoidf_(ov) * tanhf(cn);
                    out[(size_t)row * OUTS + 1 + h] = hn;
                    out[(size_t)row * OUTS + 1 + Hdim + h] = cn;
                }
            }
        }
    } else {
        // ============ loss: 32 rows x 80 logits, K=256, single-buffered ============
        float* Wlbuf = (float*)smem;              // 80 x 32 f32
        float* Vbuf  = (float*)(smem + 10240);    // 32 x 32 f32
        float* Lg    = (float*)(smem + 14336);    // 32 x 84 f32
        int m2 = myk;

        int xr = w * 8 + lrow8;
        int xrow = __shfl(reg_row, xr);
        int xg = lslot ^ swz(xr);

        f32x4 a0[2], a1[2];
        #pragma unroll
        for (int m = 0; m < 2; m++) { a0[m] = (f32x4){0.f,0.f,0.f,0.f}; a1[m] = (f32x4){0.f,0.f,0.f,0.f}; }

        for (int st = 0; st < 8; st++) {
            int ko = st * 32;
            __syncthreads();
            for (int n = w; n < 10; n += 4) {
                int r = n * 8 + lrow8;
                int g = lslot ^ swz(r);
                const float* srcW;
                if (r < 64)      srcW = Wlin + ((size_t)m2 * Vdim + r) * Hdim;
                else if (r < 66) srcW = Wec + (size_t)(r - 64) * Hdim;
                else if (r < 71) srcW = Wrel + (size_t)(r - 66) * Hdim;
                else             srcW = Wlin + (size_t)m2 * Vdim * Hdim;
                gl_lds16(srcW + ko + g * 4, Wlbuf + n * 8 * 32);
            }
            gl_lds16(vec + (size_t)xrow * Hdim + ko + xg * 4, Vbuf + (w * 8) * 32);
            __syncthreads();

            bf16x8 af[2];
            #pragma unroll
            for (int m = 0; m < 2; m++) {
                int row = m * 16 + l15;
                float4 lo = *(float4*)(Vbuf + row * 32 + p0 * 4);
                float4 hi = *(float4*)(Vbuf + row * 32 + (p0 ^ 1) * 4);
                af[m] = cvt8(lo, hi);
            }
            {
                int row = w * 16 + l15;
                float4 lo = *(float4*)(Wlbuf + row * 32 + p0 * 4);
                float4 hi = *(float4*)(Wlbuf + row * 32 + (p0 ^ 1) * 4);
                bf16x8 b0 = cvt8(lo, hi);
                a0[0] = __builtin_amdgcn_mfma_f32_16x16x32_bf16(af[0], b0, a0[0], 0, 0, 0);
                a0[1] = __builtin_amdgcn_mfma_f32_16x16x32_bf16(af[1], b0, a0[1], 0, 0, 0);
            }
            if (w == 3) {
                int row = 64 + l15;
                float4 lo = *(float4*)(Wlbuf + row * 32 + p0 * 4);
                float4 hi = *(float4*)(Wlbuf + row * 32 + (p0 ^ 1) * 4);
                bf16x8 b1 = cvt8(lo, hi);
                a1[0] = __builtin_amdgcn_mfma_f32_16x16x32_bf16(af[0], b1, a1[0], 0, 0, 0);
                a1[1] = __builtin_amdgcn_mfma_f32_16x16x32_bf16(af[1], b1, a1[1], 0, 0, 0);
            }
        }
        __syncthreads();
        {
            int col = w * 16 + l15;
            float bb = blin[m2 * Vdim + col];
            #pragma unroll
            for (int m = 0; m < 2; m++)
                #pragma unroll
                for (int reg = 0; reg < 4; reg++)
                    Lg[(m * 16 + quad * 4 + reg) * 84 + col] = a0[m][reg] + bb;
            if (w == 3) {
                int col1 = 64 + l15;
                float bb1 = (l15 < 2) ? bec[l15] : ((l15 < 7) ? brel[l15 - 2] : 0.f);
                #pragma unroll
                for (int m = 0; m < 2; m++)
                    #pragma unroll
                    for (int reg = 0; reg < 4; reg++)
                        Lg[(m * 16 + quad * 4 + reg) * 84 + col1] = a1[m][reg] + bb1;
            }
        }
        __syncthreads();
        for (int rr = 0; rr < 8; rr++) {
            int r = w * 8 + rr;
            if (r >= rcount) break;
            int orig = __shfl(reg_row, r);
            float lg = Lg[r * 84 + l];
            float mx = lg;
            for (int ss = 32; ss >= 1; ss >>= 1) mx = fmaxf(mx, __shfl_xor(mx, ss));
            float sm = expf(lg - mx);
            for (int ss = 32; ss >= 1; ss >>= 1) sm += __shfl_xor(sm, ss);
            float lt = __shfl(lg, true_idx[orig]);
            float loss = mx + logf(sm) - lt;
            if (l == 0) {
                float l0 = Lg[r * 84 + 64], l1 = Lg[r * 84 + 65];
                float me2 = fmaxf(l0, l1);
                loss += me2 + logf(expf(l0 - me2) + expf(l1 - me2)) - ((ec_idx[orig] == 0) ? l0 : l1);
                float rl[5] = { Lg[r * 84 + 66], Lg[r * 84 + 67], Lg[r * 84 + 68], Lg[r * 84 + 69], Lg[r * 84 + 70] };
                float mr = rl[0];
                #pragma unroll
                for (int i = 1; i < 5; i++) mr = fmaxf(mr, rl[i]);
                float sr = 0.f;
                #pragma unroll
                for (int i = 0; i < 5; i++) sr += expf(rl[i] - mr);
                loss += mr + logf(sr) - rl[rel_idx[orig]];
                out[(size_t)orig * OUTS] = loss;
            }
        }
    }
}

extern "C" void kernel_launch(void* const* d_in, const int* in_sizes, int n_in,
                              void* d_out, int out_size, void* d_ws, size_t ws_size,
                              hipStream_t stream) {
    const float* vec      = (const float*)d_in[0];
    const float* inp      = (const float*)d_in[1];
    const float* h_prev   = (const float*)d_in[2];
    const float* c_prev   = (const float*)d_in[3];
    const float* Wlin     = (const float*)d_in[4];
    const float* blin     = (const float*)d_in[5];
    const float* Wec      = (const float*)d_in[6];
    const float* bec      = (const float*)d_in[7];
    const float* Wrel     = (const float*)d_in[8];
    const float* brel     = (const float*)d_in[9];
    const float* W_ih     = (const float*)d_in[10];
    const float* b_ih     = (const float*)d_in[11];
    const float* W_hh     = (const float*)d_in[12];
    const float* b_hh     = (const float*)d_in[13];
    const int*   category = (const int*)d_in[14];
    const int*   cell_id  = (const int*)d_in[15];
    const int*   true_idx = (const int*)d_in[16];
    const int*   ec_idx   = (const int*)d_in[17];
    const int*   rel_idx  = (const int*)d_in[18];
    float* out = (float*)d_out;

    k_all<<<GRID, 256, DYN_LDS, stream>>>(
        vec, inp, h_prev, c_prev, Wlin, blin, Wec, bec, Wrel, brel,
        W_ih, b_ih, W_hh, b_hh, category, cell_id, true_idx, ec_idx, rel_idx, out);
}

// Round 11
// 154.621 us; speedup vs baseline: 1.0281x; 1.0281x over previous
//
#include <hip/hip_runtime.h>
#include <hip/hip_bf16.h>
#include <math.h>

#define Nn 4096
#define Hdim 256
#define Edim 128
#define Cdim 32
#define Vdim 64
#define Kdim 20
#define G4H 1024
#define OUTS 513

#define NB 8
#define LMAXL 96            // max lstm tiles per bucket (worst case 73)
#define MAXG (NB * LMAXL)   // 768 lstm slots
#define MAXT2 192           // loss slots (worst case 159)
#define GRID (MAXG + MAXT2)

typedef short bf16x8 __attribute__((ext_vector_type(8)));
typedef float f32x4 __attribute__((ext_vector_type(4)));

__device__ __forceinline__ float sigmoidf_(float x) { return 1.0f / (1.0f + expf(-x)); }

__device__ __forceinline__ bf16x8 cvt8(float4 f0, float4 f1) {
    bf16x8 r;
    __hip_bfloat16 h;
    h = __float2bfloat16(f0.x); r[0] = *(short*)&h;
    h = __float2bfloat16(f0.y); r[1] = *(short*)&h;
    h = __float2bfloat16(f0.z); r[2] = *(short*)&h;
    h = __float2bfloat16(f0.w); r[3] = *(short*)&h;
    h = __float2bfloat16(f1.x); r[4] = *(short*)&h;
    h = __float2bfloat16(f1.y); r[5] = *(short*)&h;
    h = __float2bfloat16(f1.z); r[6] = *(short*)&h;
    h = __float2bfloat16(f1.w); r[7] = *(short*)&h;
    return r;
}

__device__ __forceinline__ void gl_lds16(const float* g, void* l) {
    __builtin_amdgcn_global_load_lds((const __attribute__((address_space(1))) void*)g,
                                     (__attribute__((address_space(3))) void*)l, 16, 0, 0);
}

__device__ __forceinline__ int swz(int r) { return ((r & 3) << 1) | ((r >> 2) & 1); }

// ================= single fused kernel =================
__global__ __launch_bounds__(256, 4) void k_all(
    const float* __restrict__ vec, const float* __restrict__ inp,
    const float* __restrict__ h_prev, const float* __restrict__ c_prev,
    const float* __restrict__ Wlin, const float* __restrict__ blin,
    const float* __restrict__ Wec, const float* __restrict__ bec,
    const float* __restrict__ Wrel, const float* __restrict__ brel,
    const float* __restrict__ W_ih, const float* __restrict__ b_ih,
    const float* __restrict__ W_hh, const float* __restrict__ b_hh,
    const int* __restrict__ category, const int* __restrict__ cell_id,
    const int* __restrict__ true_idx, const int* __restrict__ ec_idx, const int* __restrict__ rel_idx,
    float* __restrict__ out)
{
    __shared__ __align__(16) char smem[40960];
    int* cntR = (int*)smem;                 // setup scratch: 32*16 replicas (2 KB)
    int* cntF = (int*)(smem + 8192);        // final counts (32 ints)
    int* wsum = (int*)(smem + 8320);        // 4 ints
    int* rows_tmp = (int*)(smem + 8448);    // 64 ints

    int t = threadIdx.x;
    int w = t >> 6, l = t & 63;
    int l15 = l & 15, quad = l >> 4;
    int lrow8 = l >> 3, lslot = l & 7;
    bool is_lstm = blockIdx.x < MAXG;
    const int* key = is_lstm ? cell_id : category;
    int nbins = is_lstm ? Kdim : Cdim;

    // ---- histogram (x16 replicated) ----
    for (int i = t; i < nbins * 16; i += 256) cntR[i] = 0;
    __syncthreads();
    int4 kv0 = ((const int4*)key)[t * 4 + 0];
    int4 kv1 = ((const int4*)key)[t * 4 + 1];
    int4 kv2 = ((const int4*)key)[t * 4 + 2];
    int4 kv3 = ((const int4*)key)[t * 4 + 3];
    int ks[16] = { kv0.x, kv0.y, kv0.z, kv0.w, kv1.x, kv1.y, kv1.z, kv1.w,
                   kv2.x, kv2.y, kv2.z, kv2.w, kv3.x, kv3.y, kv3.z, kv3.w };
    int rep = t & 15;
    #pragma unroll
    for (int j = 0; j < 16; j++) atomicAdd(&cntR[ks[j] * 16 + rep], 1);
    __syncthreads();
    if (t < nbins) {
        int s2 = 0;
        #pragma unroll
        for (int r2 = 0; r2 < 16; r2++) s2 += cntR[t * 16 + r2];
        cntF[t] = s2;
    }
    __syncthreads();

    // ---- direct slot decode (no map array) ----
    int myk, s_idx, hb0 = 0, rcount, wlen;
    if (is_lstm) {
        int b = blockIdx.x & 7, pos = blockIdx.x >> 3;
        int u = -1, sf = 0, acc = 0;
        for (int uu = b; uu < Kdim * 4; uu += NB) {
            int n = (cntF[uu >> 2] + 63) >> 6;
            if (u < 0 && pos < acc + n) { u = uu; sf = pos - acc; }
            acc += n;
        }
        if (u < 0) return;
        myk = u >> 2; hb0 = (u & 3) * 64; s_idx = sf;
        wlen = 64;
        rcount = min(64, cntF[myk] - s_idx * 64);
    } else {
        int slot = blockIdx.x - MAXG;
        int u = -1, sf = 0, acc = 0;
        for (int m = 0; m < Cdim; m++) {
            int n = (cntF[m] + 31) >> 5;
            if (u < 0 && slot < acc + n) { u = m; sf = slot - acc; }
            acc += n;
        }
        if (u < 0) return;
        myk = u; s_idx = sf;
        wlen = 32;
        rcount = min(32, cntF[myk] - s_idx * 32);
    }

    // ---- rank-select via wave shfl scan ----
    {
        int local = 0;
        #pragma unroll
        for (int j = 0; j < 16; j++) local += (ks[j] == myk) ? 1 : 0;
        int v = local;
        #pragma unroll
        for (int off = 1; off < 64; off <<= 1) {
            int n = __shfl_up(v, off);
            if (l >= off) v += n;
        }
        if (l == 63) wsum[w] = v;
        __syncthreads();
        int wbase = 0;
        #pragma unroll
        for (int ww = 0; ww < 4; ww++) wbase += (ww < w) ? wsum[ww] : 0;
        int rank = wbase + v - local;
        int w0 = s_idx * wlen;
        #pragma unroll
        for (int j = 0; j < 16; j++) {
            if (ks[j] == myk) {
                int rr = rank - w0;
                if (rr >= 0 && rr < wlen) rows_tmp[rr] = t * 16 + j;
                rank++;
            }
        }
        __syncthreads();
        if (t < wlen && t >= rcount) rows_tmp[t] = rows_tmp[0];
        __syncthreads();
    }
    int reg_row = rows_tmp[is_lstm ? l : (l & 31)];
    int swz_l = swz(l15);
    int p0 = (quad * 2) ^ swz_l;

    if (is_lstm) {
        // ============ LSTM: 64 rows x (64 h x 4 gates), K=384, fp32 DMA BK=32 ============
        float* Wbuf = (float*)smem;            // 256 x 32 f32 (32 KB)
        float* Xbuf = (float*)(smem + 32768);  // 64 x 32 f32 (8 KB)
        const float* Wih_k = W_ih + (size_t)myk * G4H * Edim;
        const float* Whh_k = W_hh + (size_t)myk * G4H * Hdim;

        int xr0 = w * 16 + lrow8;
        int xr1 = w * 16 + 8 + lrow8;
        int xrow0 = __shfl(reg_row, xr0);
        int xrow1 = __shfl(reg_row, xr1);
        int xg0 = lslot ^ swz(xr0);
        int xg1 = lslot ^ swz(xr1);

        f32x4 acc[4][4];
        #pragma unroll
        for (int m = 0; m < 4; m++)
            #pragma unroll
            for (int g = 0; g < 4; g++)
                acc[m][g] = (f32x4){0.f, 0.f, 0.f, 0.f};

        for (int st = 0; st < 12; st++) {
            int k0 = st * 32;
            const float* Wsrc; int stride, ko;
            if (k0 < Edim) { Wsrc = Wih_k; stride = Edim; ko = k0; }
            else           { Wsrc = Whh_k; stride = Hdim; ko = k0 - Edim; }
            const float* Xs0 = (k0 < Edim) ? inp + (size_t)xrow0 * Edim + ko
                                           : h_prev + (size_t)xrow0 * Hdim + (ko - 0);
            const float* Xs1 = (k0 < Edim) ? inp + (size_t)xrow1 * Edim + ko
                                           : h_prev + (size_t)xrow1 * Hdim + (ko - 0);
            __syncthreads();
            #pragma unroll
            for (int j = 0; j < 8; j++) {
                int r = w * 64 + j * 8 + lrow8;
                int g = lslot ^ swz(r);
                int gate = r >> 6, hl = r & 63;
                gl_lds16(Wsrc + (size_t)(gate * Hdim + hb0 + hl) * stride + ko + g * 4,
                         Wbuf + (w * 64 + j * 8) * 32);
            }
            gl_lds16(Xs0 + xg0 * 4, Xbuf + (w * 16) * 32);
            gl_lds16(Xs1 + xg1 * 4, Xbuf + (w * 16 + 8) * 32);
            __syncthreads();

            bf16x8 af[4], bfr[4];
            #pragma unroll
            for (int m = 0; m < 4; m++) {
                int row = m * 16 + l15;
                float4 lo = *(float4*)(Xbuf + row * 32 + p0 * 4);
                float4 hi = *(float4*)(Xbuf + row * 32 + (p0 ^ 1) * 4);
                af[m] = cvt8(lo, hi);
            }
            #pragma unroll
            for (int g = 0; g < 4; g++) {
                int row = g * 64 + w * 16 + l15;
                float4 lo = *(float4*)(Wbuf + row * 32 + p0 * 4);
                float4 hi = *(float4*)(Wbuf + row * 32 + (p0 ^ 1) * 4);
                bfr[g] = cvt8(lo, hi);
            }
            #pragma unroll
            for (int m = 0; m < 4; m++)
                #pragma unroll
                for (int g = 0; g < 4; g++)
                    acc[m][g] = __builtin_amdgcn_mfma_f32_16x16x32_bf16(af[m], bfr[g], acc[m][g], 0, 0, 0);
        }

        int h = hb0 + w * 16 + l15;
        float bs[4];
        #pragma unroll
        for (int g = 0; g < 4; g++)
            bs[g] = b_ih[(size_t)myk * G4H + g * Hdim + h] + b_hh[(size_t)myk * G4H + g * Hdim + h];

        #pragma unroll
        for (int m = 0; m < 4; m++) {
            #pragma unroll
            for (int reg = 0; reg < 4; reg++) {
                int r = m * 16 + quad * 4 + reg;
                int row = __shfl(reg_row, r);
                if (r < rcount) {
                    float iv = acc[m][0][reg] + bs[0];
                    float fv = acc[m][1][reg] + bs[1];
                    float gv = acc[m][2][reg] + bs[2];
                    float ov = acc[m][3][reg] + bs[3];
                    float cp = c_prev[(size_t)row * Hdim + h];
                    float cn = sigmoidf_(fv) * cp + sigmoidf_(iv) * tanhf(gv);
                    float hn = sigmoidf_(ov) * tanhf(cn);
                    out[(size_t)row * OUTS + 1 + h] = hn;
                    out[(size_t)row * OUTS + 1 + Hdim + h] = cn;
                }
            }
        }
    } else {
        // ============ loss: 32 rows x 80 logits, K=256, fp32 DMA BK=32 ============
        float* Wlbuf = (float*)smem;              // 80 x 32 f32 (10240 B)
        float* Vbuf  = (float*)(smem + 10240);    // 32 x 32 f32 (4096 B)
        float* Lg    = (float*)(smem + 14336);    // 32 x 84 f32 (10752 B)
        int m2 = myk;

        int xr = w * 8 + lrow8;
        int xrow = __shfl(reg_row, xr);
        int xg = lslot ^ swz(xr);

        f32x4 a0[2], a1[2];
        #pragma unroll
        for (int m = 0; m < 2; m++) { a0[m] = (f32x4){0.f,0.f,0.f,0.f}; a1[m] = (f32x4){0.f,0.f,0.f,0.f}; }

        for (int st = 0; st < 8; st++) {
            int ko = st * 32;
            __syncthreads();
            for (int n = w; n < 10; n += 4) {
                int r = n * 8 + lrow8;
                int g = lslot ^ swz(r);
                const float* srcW;
                if (r < 64)      srcW = Wlin + ((size_t)m2 * Vdim + r) * Hdim;
                else if (r < 66) srcW = Wec + (size_t)(r - 64) * Hdim;
                else if (r < 71) srcW = Wrel + (size_t)(r - 66) * Hdim;
                else             srcW = Wlin + (size_t)m2 * Vdim * Hdim;
                gl_lds16(srcW + ko + g * 4, Wlbuf + n * 8 * 32);
            }
            gl_lds16(vec + (size_t)xrow * Hdim + ko + xg * 4, Vbuf + (w * 8) * 32);
            __syncthreads();

            bf16x8 af[2];
            #pragma unroll
            for (int m = 0; m < 2; m++) {
                int row = m * 16 + l15;
                float4 lo = *(float4*)(Vbuf + row * 32 + p0 * 4);
                float4 hi = *(float4*)(Vbuf + row * 32 + (p0 ^ 1) * 4);
                af[m] = cvt8(lo, hi);
            }
            {
                int row = w * 16 + l15;
                float4 lo = *(float4*)(Wlbuf + row * 32 + p0 * 4);
                float4 hi = *(float4*)(Wlbuf + row * 32 + (p0 ^ 1) * 4);
                bf16x8 b0 = cvt8(lo, hi);
                a0[0] = __builtin_amdgcn_mfma_f32_16x16x32_bf16(af[0], b0, a0[0], 0, 0, 0);
                a0[1] = __builtin_amdgcn_mfma_f32_16x16x32_bf16(af[1], b0, a0[1], 0, 0, 0);
            }
            if (w == 3) {
                int row = 64 + l15;
                float4 lo = *(float4*)(Wlbuf + row * 32 + p0 * 4);
                float4 hi = *(float4*)(Wlbuf + row * 32 + (p0 ^ 1) * 4);
                bf16x8 b1 = cvt8(lo, hi);
                a1[0] = __builtin_amdgcn_mfma_f32_16x16x32_bf16(af[0], b1, a1[0], 0, 0, 0);
                a1[1] = __builtin_amdgcn_mfma_f32_16x16x32_bf16(af[1], b1, a1[1], 0, 0, 0);
            }
        }
        __syncthreads();
        {
            int col = w * 16 + l15;
            float bb = blin[m2 * Vdim + col];
            #pragma unroll
            for (int m = 0; m < 2; m++)
                #pragma unroll
                for (int reg = 0; reg < 4; reg++)
                    Lg[(m * 16 + quad * 4 + reg) * 84 + col] = a0[m][reg] + bb;
            if (w == 3) {
                int col1 = 64 + l15;
                float bb1 = (l15 < 2) ? bec[l15] : ((l15 < 7) ? brel[l15 - 2] : 0.f);
                #pragma unroll
                for (int m = 0; m < 2; m++)
                    #pragma unroll
                    for (int reg = 0; reg < 4; reg++)
                        Lg[(m * 16 + quad * 4 + reg) * 84 + col1] = a1[m][reg] + bb1;
            }
        }
        __syncthreads();
        for (int rr = 0; rr < 8; rr++) {
            int r = w * 8 + rr;
            if (r >= rcount) break;
            int orig = __shfl(reg_row, r);
            float lg = Lg[r * 84 + l];
            float mx = lg;
            for (int ss = 32; ss >= 1; ss >>= 1) mx = fmaxf(mx, __shfl_xor(mx, ss));
            float sm = expf(lg - mx);
            for (int ss = 32; ss >= 1; ss >>= 1) sm += __shfl_xor(sm, ss);
            float lt = __shfl(lg, true_idx[orig]);
            float loss = mx + logf(sm) - lt;
            if (l == 0) {
                float l0 = Lg[r * 84 + 64], l1 = Lg[r * 84 + 65];
                float me2 = fmaxf(l0, l1);
                loss += me2 + logf(expf(l0 - me2) + expf(l1 - me2)) - ((ec_idx[orig] == 0) ? l0 : l1);
                float rl[5] = { Lg[r * 84 + 66], Lg[r * 84 + 67], Lg[r * 84 + 68], Lg[r * 84 + 69], Lg[r * 84 + 70] };
                float mr = rl[0];
                #pragma unroll
                for (int i = 1; i < 5; i++) mr = fmaxf(mr, rl[i]);
                float sr = 0.f;
                #pragma unroll
                for (int i = 0; i < 5; i++) sr += expf(rl[i] - mr);
                loss += mr + logf(sr) - rl[rel_idx[orig]];
                out[(size_t)orig * OUTS] = loss;
            }
        }
    }
}

extern "C" void kernel_launch(void* const* d_in, const int* in_sizes, int n_in,
                              void* d_out, int out_size, void* d_ws, size_t ws_size,
                              hipStream_t stream) {
    const float* vec      = (const float*)d_in[0];
    const float* inp      = (const float*)d_in[1];
    const float* h_prev   = (const float*)d_in[2];
    const float* c_prev   = (const float*)d_in[3];
    const float* Wlin     = (const float*)d_in[4];
    const float* blin     = (const float*)d_in[5];
    const float* Wec      = (const float*)d_in[6];
    const float* bec      = (const float*)d_in[7];
    const float* Wrel     = (const float*)d_in[8];
    const float* brel     = (const float*)d_in[9];
    const float* W_ih     = (const float*)d_in[10];
    const float* b_ih     = (const float*)d_in[11];
    const float* W_hh     = (const float*)d_in[12];
    const float* b_hh     = (const float*)d_in[13];
    const int*   category = (const int*)d_in[14];
    const int*   cell_id  = (const int*)d_in[15];
    const int*   true_idx = (const int*)d_in[16];
    const int*   ec_idx   = (const int*)d_in[17];
    const int*   rel_idx  = (const int*)d_in[18];
    float* out = (float*)d_out;

    k_all<<<GRID, 256, 0, stream>>>(
        vec, inp, h_prev, c_prev, Wlin, blin, Wec, bec, Wrel, brel,
        W_ih, b_ih, W_hh, b_hh, category, cell_id, true_idx, ec_idx, rel_idx, out);
}